// Round 1
// baseline (5491.352 us; speedup 1.0000x reference)
//
#include <hip/hip_runtime.h>

typedef unsigned short u16;
typedef unsigned int   u32;
typedef float f32x2 __attribute__((ext_vector_type(2)));
typedef float f32x4 __attribute__((ext_vector_type(4)));
typedef u32   u32x4 __attribute__((ext_vector_type(4)));
typedef __bf16 bf16x8 __attribute__((ext_vector_type(8)));

#define NN  100000
#define EE  1600000
#define FIN 1024
#define DD  128
#define D2  256
#define LL  4
#define GG  64

__device__ __forceinline__ u16 f2bf(float f) {
  u32 u = __builtin_bit_cast(u32, f);
  u32 r = (u + 0x7fffu + ((u >> 16) & 1u)) >> 16;
  return (u16)r;
}
__device__ __forceinline__ float bf2f(u16 h) {
  return __builtin_bit_cast(float, (u32)h << 16);
}

// ---------------- weight transpose+convert: dst[mat][n][k] = bf16(src[mat][k][n])
__global__ void wconv_k(const float* __restrict__ src, u16* __restrict__ dst,
                        int K, int Ncols, int total) {
  int i = blockIdx.x * 256 + threadIdx.x;
  if (i >= total) return;
  int kn = K * Ncols;
  int mat = i / kn;
  int r = i - mat * kn;
  int k = r / Ncols;
  int n = r - k * Ncols;
  dst[mat * kn + n * K + k] = f2bf(src[i]);
}

// ---------------- CSR build ----------------
__global__ void hist_k(const int* __restrict__ dstv, int* __restrict__ deg, int ne) {
  int e = blockIdx.x * 256 + threadIdx.x;
  if (e < ne) atomicAdd(&deg[dstv[e]], 1);
}

__global__ void scan1_k(const int* __restrict__ deg, int* __restrict__ bsum, int n) {
  __shared__ int s[256];
  int i = blockIdx.x * 256 + threadIdx.x;
  s[threadIdx.x] = (i < n) ? deg[i] : 0;
  __syncthreads();
  for (int st = 128; st > 0; st >>= 1) {
    if (threadIdx.x < st) s[threadIdx.x] += s[threadIdx.x + st];
    __syncthreads();
  }
  if (threadIdx.x == 0) bsum[blockIdx.x] = s[0];
}

__global__ void scan2_k(int* __restrict__ bsum, int nb) { // 1 block, 512 threads
  __shared__ int s[512];
  int t = threadIdx.x;
  int v0 = (t < nb) ? bsum[t] : 0;
  s[t] = v0;
  __syncthreads();
  for (int st = 1; st < 512; st <<= 1) {
    int v = (t >= st) ? s[t - st] : 0;
    __syncthreads();
    s[t] += v;
    __syncthreads();
  }
  if (t < nb) bsum[t] = s[t] - v0;  // exclusive
  if (t == 0) bsum[nb] = s[511];    // total
}

__global__ void scan3_k(const int* __restrict__ deg, const int* __restrict__ bsum,
                        int* __restrict__ rowp, int n, int nb) {
  __shared__ int s[256];
  int t = threadIdx.x;
  int i = blockIdx.x * 256 + t;
  int v0 = (i < n) ? deg[i] : 0;
  s[t] = v0;
  __syncthreads();
  for (int st = 1; st < 256; st <<= 1) {
    int v = (t >= st) ? s[t - st] : 0;
    __syncthreads();
    s[t] += v;
    __syncthreads();
  }
  if (i < n) rowp[i] = s[t] - v0 + bsum[blockIdx.x];
  if (i == 0) rowp[n] = bsum[nb];
}

__global__ void fill_k(const int* __restrict__ srcv, const int* __restrict__ dstv,
                       int* __restrict__ cur, int* __restrict__ colx, int ne) {
  int e = blockIdx.x * 256 + threadIdx.x;
  if (e < ne) {
    int d = dstv[e];
    int p = atomicAdd(&cur[d], 1);
    colx[p] = srcv[e];
  }
}

// ---------------- zin = (1+eps)*h + sum_{src in-edges} h[src]  (bf16 out) -------
__global__ __launch_bounds__(256) void zin_k(
    const float* __restrict__ h, const u32* __restrict__ hb,
    const int* __restrict__ rowp, const int* __restrict__ colx,
    const float* __restrict__ epsp, u32* __restrict__ zout, int n) {
  int node = (blockIdx.x * 256 + threadIdx.x) >> 6;
  int lane = threadIdx.x & 63;
  if (node >= n) return;
  int r0 = rowp[node], r1 = rowp[node + 1];
  float a0 = 0.f, a1 = 0.f;
  for (int e = r0; e < r1; e++) {
    int s = colx[e];
    u32 u = hb[s * 64 + lane];
    a0 += __builtin_bit_cast(float, u << 16);
    a1 += __builtin_bit_cast(float, u & 0xffff0000u);
  }
  float ep = 1.0f + epsp[0];
  f32x2 hv = *(const f32x2*)(h + (size_t)node * 128 + lane * 2);
  float z0 = ep * hv[0] + a0;
  float z1 = ep * hv[1] + a1;
  zout[(size_t)node * 64 + lane] = (u32)f2bf(z0) | ((u32)f2bf(z1) << 16);
}

// ---------------- MFMA GEMM template ----------------
// AMODE: 0 = A fp32 (convert to bf16), 1 = A bf16, 2 = A bf16 + BN scale/shift + relu
// EPI:   0 = +bias, write f32+bf16
//        1 = +bias, write bf16, accumulate column sum/sumsq -> stats
//        2 = +bias + residual(hio), relu, write f32+bf16
//        3 = +bias, relu, write f32+bf16
template<int AMODE, int EPI>
__global__ __launch_bounds__(256) void gemm_k(
    const void* __restrict__ Ap, const u16* __restrict__ Bt,
    const float* __restrict__ bias, const float* __restrict__ ss,
    float* __restrict__ hio, u16* __restrict__ obf,
    float* __restrict__ stats, int M, int K, int Ncols) {
  __shared__ alignas(16) u16 As[128][40];
  __shared__ alignas(16) u16 Bs[128][40];
  __shared__ float ssS[512];
  __shared__ float statS[256];

  const int t = threadIdx.x;
  const int w = t >> 6, l = t & 63;
  const int wm = (w >> 1) * 64, wn = (w & 1) * 64;
  const int quad = l >> 4, cl = l & 15;
  const int m0 = blockIdx.x * 128, n0 = blockIdx.y * 128;
  const int rs = t >> 1, kq = (t & 1) * 16;
  const int gm = m0 + rs;
  const int gn = n0 + rs;

  if constexpr (AMODE == 2) {
    for (int i = t; i < 2 * K; i += 256) ssS[i] = ss[i];
    __syncthreads();
  }

  f32x4 acc[4][4];
#pragma unroll
  for (int i = 0; i < 4; i++)
#pragma unroll
    for (int j = 0; j < 4; j++)
#pragma unroll
      for (int v = 0; v < 4; v++) acc[i][j][v] = 0.f;

  for (int k0 = 0; k0 < K; k0 += 32) {
    // stage A (128 x 32 bf16)
    {
      u16 tmp[16];
      if constexpr (AMODE == 0) {
        if (gm < M) {
          const float* a = (const float*)Ap + (size_t)gm * K + k0 + kq;
#pragma unroll
          for (int j = 0; j < 16; j += 4) {
            f32x4 v = *(const f32x4*)(a + j);
            tmp[j] = f2bf(v[0]); tmp[j + 1] = f2bf(v[1]);
            tmp[j + 2] = f2bf(v[2]); tmp[j + 3] = f2bf(v[3]);
          }
        } else {
#pragma unroll
          for (int j = 0; j < 16; j++) tmp[j] = 0;
        }
      } else {
        if (gm < M) {
          const u16* a = (const u16*)Ap + (size_t)gm * K + k0 + kq;
          *(u32x4*)&tmp[0] = *(const u32x4*)a;
          *(u32x4*)&tmp[8] = *(const u32x4*)(a + 8);
          if constexpr (AMODE == 2) {
#pragma unroll
            for (int j = 0; j < 16; j++) {
              int k = k0 + kq + j;
              float f = bf2f(tmp[j]);
              f = f * ssS[k] + ssS[K + k];
              f = fmaxf(f, 0.f);
              tmp[j] = f2bf(f);
            }
          }
        } else {
#pragma unroll
          for (int j = 0; j < 16; j++) tmp[j] = 0;
        }
      }
      *(u32x4*)&As[rs][kq] = *(const u32x4*)&tmp[0];
      *(u32x4*)&As[rs][kq + 8] = *(const u32x4*)&tmp[8];
    }
    // stage B (128 x 32 bf16), rows = output cols (Bt is [Ncols][K])
    {
      if (gn < Ncols) {
        const u16* b = Bt + (size_t)gn * K + k0 + kq;
        *(u32x4*)&Bs[rs][kq] = *(const u32x4*)b;
        *(u32x4*)&Bs[rs][kq + 8] = *(const u32x4*)(b + 8);
      } else {
        u32x4 z = {0u, 0u, 0u, 0u};
        *(u32x4*)&Bs[rs][kq] = z;
        *(u32x4*)&Bs[rs][kq + 8] = z;
      }
    }
    __syncthreads();
    bf16x8 af[4], bfr[4];
#pragma unroll
    for (int i = 0; i < 4; i++)
      af[i] = __builtin_bit_cast(bf16x8, *(const u32x4*)&As[wm + 16 * i + cl][quad * 8]);
#pragma unroll
    for (int j = 0; j < 4; j++)
      bfr[j] = __builtin_bit_cast(bf16x8, *(const u32x4*)&Bs[wn + 16 * j + cl][quad * 8]);
#pragma unroll
    for (int i = 0; i < 4; i++)
#pragma unroll
      for (int j = 0; j < 4; j++)
        acc[i][j] = __builtin_amdgcn_mfma_f32_16x16x32_bf16(af[i], bfr[j], acc[i][j], 0, 0, 0);
    __syncthreads();
  }

  // epilogue
  float sj[4], s2j[4];
  if constexpr (EPI == 1) {
#pragma unroll
    for (int j = 0; j < 4; j++) { sj[j] = 0.f; s2j[j] = 0.f; }
  }
#pragma unroll
  for (int j = 0; j < 4; j++) {
    int c = n0 + wn + 16 * j + cl;
    bool cv = (c < Ncols);
    float bv = cv ? bias[c] : 0.f;
#pragma unroll
    for (int i = 0; i < 4; i++) {
      int rbase = m0 + wm + 16 * i + 4 * quad;
#pragma unroll
      for (int v = 0; v < 4; v++) {
        int rr = rbase + v;
        if (rr < M && cv) {
          float val = acc[i][j][v] + bv;
          size_t idx = (size_t)rr * Ncols + c;
          if constexpr (EPI == 0) {
            hio[idx] = val;
            obf[idx] = f2bf(val);
          } else if constexpr (EPI == 1) {
            obf[idx] = f2bf(val);
            sj[j] += val; s2j[j] += val * val;
          } else if constexpr (EPI == 2) {
            val += hio[idx];
            val = fmaxf(val, 0.f);
            hio[idx] = val;
            obf[idx] = f2bf(val);
          } else {
            val = fmaxf(val, 0.f);
            hio[idx] = val;
            obf[idx] = f2bf(val);
          }
        }
      }
    }
  }
  if constexpr (EPI == 1) {
    __syncthreads();
    statS[t < 256 ? t : 0] = 0.f;
    __syncthreads();
#pragma unroll
    for (int j = 0; j < 4; j++) {
      float s = sj[j], s2 = s2j[j];
      s += __shfl_xor(s, 16, 64);  s2 += __shfl_xor(s2, 16, 64);
      s += __shfl_xor(s, 32, 64);  s2 += __shfl_xor(s2, 32, 64);
      if (quad == 0) {
        int c = wn + 16 * j + cl;
        atomicAdd(&statS[c], s);
        atomicAdd(&statS[128 + c], s2);
      }
    }
    __syncthreads();
    if (t < 128) {
      atomicAdd(&stats[n0 + t], statS[t]);
      atomicAdd(&stats[Ncols + n0 + t], statS[128 + t]);
    }
  }
}

// ---------------- BN finalize: scale/shift ----------------
__global__ void bnfin_k(const float* __restrict__ stats, const float* __restrict__ g,
                        const float* __restrict__ be, float* __restrict__ ss, float inv_n) {
  int c = threadIdx.x;  // 256
  float mu = stats[c] * inv_n;
  float var = stats[256 + c] * inv_n - mu * mu;
  float rstd = rsqrtf(var + 1e-5f);
  float sc = rstd * g[c];
  ss[c] = sc;
  ss[256 + c] = be[c] - mu * sc;
}

// ---------------- pooling ----------------
__global__ void pool_k(const float* __restrict__ h, const int* __restrict__ bat,
                       float* __restrict__ pooled, int coff, int n) {
  int idx = blockIdx.x * 256 + threadIdx.x;
  if (idx >= n * 128) return;
  int node = idx >> 7, c = idx & 127;
  atomicAdd(&pooled[bat[node] * 256 + coff + c], h[idx]);
}

__global__ void cnt_k(const int* __restrict__ bat, float* __restrict__ cnt, int n) {
  int i = blockIdx.x * 256 + threadIdx.x;
  if (i < n) atomicAdd(&cnt[bat[i]], 1.0f);
}

__global__ void pdiv_k(float* __restrict__ pooled, u16* __restrict__ pooledb,
                       const float* __restrict__ cnt, int coff) {
  int i = blockIdx.x * 256 + threadIdx.x;
  if (i >= GG * DD) return;
  int g = i >> 7, c = i & 127;
  float v = pooled[g * 256 + coff + c] / fmaxf(cnt[g], 1.0f);
  pooled[g * 256 + coff + c] = v;
  pooledb[g * 256 + coff + c] = f2bf(v);
}

// ---------------- final dot + sigmoid ----------------
__global__ void outk(const float* __restrict__ h2, const float* __restrict__ outW,
                     const float* __restrict__ outb, float* __restrict__ out) {
  int r = threadIdx.x;  // 64
  float s = outb[0];
  for (int k = 0; k < 64; k++) s += h2[r * 64 + k] * outW[k];
  out[r] = 1.0f / (1.0f + expf(-s));
}

extern "C" void kernel_launch(void* const* d_in, const int* in_sizes, int n_in,
                              void* d_out, int out_size, void* d_ws, size_t ws_size,
                              hipStream_t stream) {
  (void)in_sizes; (void)n_in; (void)out_size; (void)ws_size;
  const float* xin[2] = {(const float*)d_in[0], (const float*)d_in[3]};
  const int*   ei[2]  = {(const int*)d_in[1], (const int*)d_in[4]};
  const int*   bat[2] = {(const int*)d_in[2], (const int*)d_in[5]};
  const float *embW[2], *embB[2], *W1[2], *b1[2], *gam[2], *bet[2], *W2[2], *b2[2], *eps[2];
  for (int b = 0; b < 2; b++) {
    int o = 6 + b * 9;
    embW[b] = (const float*)d_in[o + 0]; embB[b] = (const float*)d_in[o + 1];
    W1[b]   = (const float*)d_in[o + 2]; b1[b]   = (const float*)d_in[o + 3];
    gam[b]  = (const float*)d_in[o + 4]; bet[b]  = (const float*)d_in[o + 5];
    W2[b]   = (const float*)d_in[o + 6]; b2[b]   = (const float*)d_in[o + 7];
    eps[b]  = (const float*)d_in[o + 8];
  }
  const float* fc1W = (const float*)d_in[24]; const float* fc1b = (const float*)d_in[25];
  const float* fc2W = (const float*)d_in[26]; const float* fc2b = (const float*)d_in[27];
  const float* outW = (const float*)d_in[28]; const float* outb = (const float*)d_in[29];

  char* base = (char*)d_ws; size_t off = 0;
  auto al = [&](size_t bytes) -> char* {
    char* p = base + off; off += (bytes + 255) & ~(size_t)255; return p;
  };
  float* h      = (float*)al((size_t)NN * DD * 4);
  u32*   hb     = (u32*)  al((size_t)NN * DD * 2);
  u32*   zb     = (u32*)  al((size_t)NN * DD * 2);
  u16*   tb     = (u16*)  al((size_t)NN * D2 * 2);
  int*   deg    = (int*)  al((size_t)NN * 4);
  int*   rowp   = (int*)  al((size_t)(NN + 1) * 4);
  int*   cur    = (int*)  al((size_t)NN * 4);
  int*   colx   = (int*)  al((size_t)EE * 4);
  int*   bsum   = (int*)  al(512 * 4);
  float* stats  = (float*)al(512 * 4);
  float* ssb    = (float*)al(512 * 4);
  float* pooled = (float*)al(GG * D2 * 4);
  u16*   pooledb= (u16*)  al(GG * D2 * 2);
  float* cntb   = (float*)al(GG * 4);
  u16 *embWt[2], *W1t[2], *W2t[2];
  for (int b = 0; b < 2; b++) {
    embWt[b] = (u16*)al((size_t)DD * FIN * 2);
    W1t[b]   = (u16*)al((size_t)LL * D2 * DD * 2);
    W2t[b]   = (u16*)al((size_t)LL * DD * D2 * 2);
  }
  u16*   fc1Wt = (u16*)  al(256 * 256 * 2);
  u16*   fc2Wt = (u16*)  al(64 * 256 * 2);
  float* h1f   = (float*)al(64 * 256 * 4);
  u16*   h1b   = (u16*)  al(64 * 256 * 2);
  float* h2f   = (float*)al(64 * 64 * 4);
  u16*   h2b   = (u16*)  al(64 * 64 * 2);

  hipMemsetAsync(pooled, 0, GG * D2 * 4, stream);
  for (int b = 0; b < 2; b++) {
    wconv_k<<<(DD * FIN + 255) / 256, 256, 0, stream>>>(embW[b], embWt[b], FIN, DD, FIN * DD);
    wconv_k<<<(LL * DD * D2 + 255) / 256, 256, 0, stream>>>(W1[b], W1t[b], DD, D2, LL * DD * D2);
    wconv_k<<<(LL * DD * D2 + 255) / 256, 256, 0, stream>>>(W2[b], W2t[b], D2, DD, LL * DD * D2);
  }
  wconv_k<<<(256 * 256 + 255) / 256, 256, 0, stream>>>(fc1W, fc1Wt, 256, 256, 256 * 256);
  wconv_k<<<(256 * 64 + 255) / 256, 256, 0, stream>>>(fc2W, fc2Wt, 256, 64, 256 * 64);

  const int gx = (NN + 127) / 128;
  const int nbk = (NN + 255) / 256;  // 391
  for (int b = 0; b < 2; b++) {
    const int* esrc = ei[b];
    const int* edst = ei[b] + EE;
    hipMemsetAsync(deg, 0, (size_t)NN * 4, stream);
    hist_k<<<(EE + 255) / 256, 256, 0, stream>>>(edst, deg, EE);
    scan1_k<<<nbk, 256, 0, stream>>>(deg, bsum, NN);
    scan2_k<<<1, 512, 0, stream>>>(bsum, nbk);
    scan3_k<<<nbk, 256, 0, stream>>>(deg, bsum, rowp, NN, nbk);
    hipMemcpyAsync(cur, rowp, (size_t)NN * 4, hipMemcpyDeviceToDevice, stream);
    fill_k<<<(EE + 255) / 256, 256, 0, stream>>>(esrc, edst, cur, colx, EE);

    gemm_k<0, 0><<<dim3(gx, 1), 256, 0, stream>>>(xin[b], embWt[b], embB[b], nullptr,
                                                  h, (u16*)hb, nullptr, NN, FIN, DD);
    for (int l = 0; l < LL; l++) {
      zin_k<<<(NN + 3) / 4, 256, 0, stream>>>(h, hb, rowp, colx, eps[b] + l, zb, NN);
      hipMemsetAsync(stats, 0, 512 * 4, stream);
      gemm_k<1, 1><<<dim3(gx, 2), 256, 0, stream>>>(zb, W1t[b] + l * D2 * DD, b1[b] + l * D2,
                                                    nullptr, nullptr, tb, stats, NN, DD, D2);
      bnfin_k<<<1, 256, 0, stream>>>(stats, gam[b] + l * D2, bet[b] + l * D2, ssb, 1.0f / NN);
      gemm_k<2, 2><<<dim3(gx, 1), 256, 0, stream>>>(tb, W2t[b] + l * DD * D2, b2[b] + l * DD,
                                                    ssb, h, (u16*)hb, nullptr, NN, D2, DD);
    }
    hipMemsetAsync(cntb, 0, GG * 4, stream);
    pool_k<<<(NN * DD + 255) / 256, 256, 0, stream>>>(h, bat[b], pooled, b * DD, NN);
    cnt_k<<<(NN + 255) / 256, 256, 0, stream>>>(bat[b], cntb, NN);
    pdiv_k<<<(GG * DD + 255) / 256, 256, 0, stream>>>(pooled, pooledb, cntb, b * DD);
  }
  gemm_k<1, 3><<<dim3(1, 2), 256, 0, stream>>>(pooledb, fc1Wt, fc1b, nullptr,
                                               h1f, h1b, nullptr, GG, 256, 256);
  gemm_k<1, 3><<<dim3(1, 1), 256, 0, stream>>>(h1b, fc2Wt, fc2b, nullptr,
                                               h2f, h2b, nullptr, GG, 256, 64);
  outk<<<1, 64, 0, stream>>>(h2f, outW, outb, (float*)d_out);
}

// Round 2
// 4209.423 us; speedup vs baseline: 1.3045x; 1.3045x over previous
//
#include <hip/hip_runtime.h>

typedef unsigned short u16;
typedef unsigned int   u32;
typedef float f32x2 __attribute__((ext_vector_type(2)));
typedef float f32x4 __attribute__((ext_vector_type(4)));
typedef u32   u32x4 __attribute__((ext_vector_type(4)));
typedef __bf16 bf16x8 __attribute__((ext_vector_type(8)));

#define NN  100000
#define EE  1600000
#define FIN 1024
#define DD  128
#define D2  256
#define LL  4
#define GG  64

__device__ __forceinline__ u16 f2bf(float f) {
  u32 u = __builtin_bit_cast(u32, f);
  u32 r = (u + 0x7fffu + ((u >> 16) & 1u)) >> 16;
  return (u16)r;
}
__device__ __forceinline__ float bf2f(u16 h) {
  return __builtin_bit_cast(float, (u32)h << 16);
}

// ---------------- weight transpose+convert: dst[mat][n][k] = bf16(src[mat][k][n])
__global__ void wconv_k(const float* __restrict__ src, u16* __restrict__ dst,
                        int K, int Ncols, int total) {
  int i = blockIdx.x * 256 + threadIdx.x;
  if (i >= total) return;
  int kn = K * Ncols;
  int mat = i / kn;
  int r = i - mat * kn;
  int k = r / Ncols;
  int n = r - k * Ncols;
  dst[mat * kn + n * K + k] = f2bf(src[i]);
}

// ---------------- CSR build ----------------
__global__ void hist_k(const int* __restrict__ dstv, int* __restrict__ deg, int ne) {
  int e = blockIdx.x * 256 + threadIdx.x;
  if (e < ne) atomicAdd(&deg[dstv[e]], 1);
}

__global__ void scan1_k(const int* __restrict__ deg, int* __restrict__ bsum, int n) {
  __shared__ int s[256];
  int i = blockIdx.x * 256 + threadIdx.x;
  s[threadIdx.x] = (i < n) ? deg[i] : 0;
  __syncthreads();
  for (int st = 128; st > 0; st >>= 1) {
    if (threadIdx.x < st) s[threadIdx.x] += s[threadIdx.x + st];
    __syncthreads();
  }
  if (threadIdx.x == 0) bsum[blockIdx.x] = s[0];
}

__global__ void scan2_k(int* __restrict__ bsum, int nb) { // 1 block, 512 threads
  __shared__ int s[512];
  int t = threadIdx.x;
  int v0 = (t < nb) ? bsum[t] : 0;
  s[t] = v0;
  __syncthreads();
  for (int st = 1; st < 512; st <<= 1) {
    int v = (t >= st) ? s[t - st] : 0;
    __syncthreads();
    s[t] += v;
    __syncthreads();
  }
  if (t < nb) bsum[t] = s[t] - v0;  // exclusive
  if (t == 0) bsum[nb] = s[511];    // total
}

__global__ void scan3_k(const int* __restrict__ deg, const int* __restrict__ bsum,
                        int* __restrict__ rowp, int n, int nb) {
  __shared__ int s[256];
  int t = threadIdx.x;
  int i = blockIdx.x * 256 + t;
  int v0 = (i < n) ? deg[i] : 0;
  s[t] = v0;
  __syncthreads();
  for (int st = 1; st < 256; st <<= 1) {
    int v = (t >= st) ? s[t - st] : 0;
    __syncthreads();
    s[t] += v;
    __syncthreads();
  }
  if (i < n) rowp[i] = s[t] - v0 + bsum[blockIdx.x];
  if (i == 0) rowp[n] = bsum[nb];
}

__global__ void fill_k(const int* __restrict__ srcv, const int* __restrict__ dstv,
                       int* __restrict__ cur, int* __restrict__ colx, int ne) {
  int e = blockIdx.x * 256 + threadIdx.x;
  if (e < ne) {
    int d = dstv[e];
    int p = atomicAdd(&cur[d], 1);
    colx[p] = srcv[e];
  }
}

// ---------------- zin = (1+eps)*h + sum_{src in-edges} h[src]  (bf16 out) -------
__global__ __launch_bounds__(256) void zin_k(
    const float* __restrict__ h, const u32* __restrict__ hb,
    const int* __restrict__ rowp, const int* __restrict__ colx,
    const float* __restrict__ epsp, u32* __restrict__ zout, int n) {
  int node = (blockIdx.x * 256 + threadIdx.x) >> 6;
  int lane = threadIdx.x & 63;
  if (node >= n) return;
  int r0 = rowp[node], r1 = rowp[node + 1];
  float a0 = 0.f, a1 = 0.f;
  for (int e = r0; e < r1; e++) {
    int s = colx[e];
    u32 u = hb[s * 64 + lane];
    a0 += __builtin_bit_cast(float, u << 16);
    a1 += __builtin_bit_cast(float, u & 0xffff0000u);
  }
  float ep = 1.0f + epsp[0];
  f32x2 hv = *(const f32x2*)(h + (size_t)node * 128 + lane * 2);
  float z0 = ep * hv[0] + a0;
  float z1 = ep * hv[1] + a1;
  zout[(size_t)node * 64 + lane] = (u32)f2bf(z0) | ((u32)f2bf(z1) << 16);
}

// ---------------- MFMA GEMM template ----------------
// AMODE: 0 = A fp32 (convert to bf16), 1 = A bf16, 2 = A bf16 + BN scale/shift + relu
// EPI:   0 = +bias, write f32+bf16
//        1 = +bias, write bf16, accumulate column sum/sumsq -> stats
//        2 = +bias + residual(hio), relu, write f32+bf16
//        3 = +bias, relu, write f32+bf16
template<int AMODE, int EPI>
__global__ __launch_bounds__(256) void gemm_k(
    const void* __restrict__ Ap, const u16* __restrict__ Bt,
    const float* __restrict__ bias, const float* __restrict__ ss,
    float* __restrict__ hio, u16* __restrict__ obf,
    float* __restrict__ stats, int M, int K, int Ncols) {
  __shared__ alignas(16) u16 As[128][40];
  __shared__ alignas(16) u16 Bs[128][40];
  __shared__ float ssS[512];
  __shared__ float statS[256];

  const int t = threadIdx.x;
  const int w = t >> 6, l = t & 63;
  const int wm = (w >> 1) * 64, wn = (w & 1) * 64;
  const int quad = l >> 4, cl = l & 15;
  const int m0 = blockIdx.x * 128, n0 = blockIdx.y * 128;
  const int rs = t >> 1, kq = (t & 1) * 16;
  const int gm = m0 + rs;
  const int gn = n0 + rs;

  if constexpr (AMODE == 2) {
    for (int i = t; i < 2 * K; i += 256) ssS[i] = ss[i];
    __syncthreads();
  }

  f32x4 acc[4][4];
#pragma unroll
  for (int i = 0; i < 4; i++)
#pragma unroll
    for (int j = 0; j < 4; j++)
#pragma unroll
      for (int v = 0; v < 4; v++) acc[i][j][v] = 0.f;

  for (int k0 = 0; k0 < K; k0 += 32) {
    // stage A (128 x 32 bf16)
    {
      u16 tmp[16];
      if constexpr (AMODE == 0) {
        if (gm < M) {
          const float* a = (const float*)Ap + (size_t)gm * K + k0 + kq;
#pragma unroll
          for (int j = 0; j < 16; j += 4) {
            f32x4 v = *(const f32x4*)(a + j);
            tmp[j] = f2bf(v[0]); tmp[j + 1] = f2bf(v[1]);
            tmp[j + 2] = f2bf(v[2]); tmp[j + 3] = f2bf(v[3]);
          }
        } else {
#pragma unroll
          for (int j = 0; j < 16; j++) tmp[j] = 0;
        }
      } else {
        if (gm < M) {
          const u16* a = (const u16*)Ap + (size_t)gm * K + k0 + kq;
          *(u32x4*)&tmp[0] = *(const u32x4*)a;
          *(u32x4*)&tmp[8] = *(const u32x4*)(a + 8);
          if constexpr (AMODE == 2) {
#pragma unroll
            for (int j = 0; j < 16; j++) {
              int k = k0 + kq + j;
              float f = bf2f(tmp[j]);
              f = f * ssS[k] + ssS[K + k];
              f = fmaxf(f, 0.f);
              tmp[j] = f2bf(f);
            }
          }
        } else {
#pragma unroll
          for (int j = 0; j < 16; j++) tmp[j] = 0;
        }
      }
      *(u32x4*)&As[rs][kq] = *(const u32x4*)&tmp[0];
      *(u32x4*)&As[rs][kq + 8] = *(const u32x4*)&tmp[8];
    }
    // stage B (128 x 32 bf16), rows = output cols (Bt is [Ncols][K])
    {
      if (gn < Ncols) {
        const u16* b = Bt + (size_t)gn * K + k0 + kq;
        *(u32x4*)&Bs[rs][kq] = *(const u32x4*)b;
        *(u32x4*)&Bs[rs][kq + 8] = *(const u32x4*)(b + 8);
      } else {
        u32x4 z = {0u, 0u, 0u, 0u};
        *(u32x4*)&Bs[rs][kq] = z;
        *(u32x4*)&Bs[rs][kq + 8] = z;
      }
    }
    __syncthreads();
    bf16x8 af[4], bfr[4];
#pragma unroll
    for (int i = 0; i < 4; i++)
      af[i] = __builtin_bit_cast(bf16x8, *(const u32x4*)&As[wm + 16 * i + cl][quad * 8]);
#pragma unroll
    for (int j = 0; j < 4; j++)
      bfr[j] = __builtin_bit_cast(bf16x8, *(const u32x4*)&Bs[wn + 16 * j + cl][quad * 8]);
#pragma unroll
    for (int i = 0; i < 4; i++)
#pragma unroll
      for (int j = 0; j < 4; j++)
        acc[i][j] = __builtin_amdgcn_mfma_f32_16x16x32_bf16(af[i], bfr[j], acc[i][j], 0, 0, 0);
    __syncthreads();
  }

  // epilogue
  float sj[4], s2j[4];
  if constexpr (EPI == 1) {
#pragma unroll
    for (int j = 0; j < 4; j++) { sj[j] = 0.f; s2j[j] = 0.f; }
  }
#pragma unroll
  for (int j = 0; j < 4; j++) {
    int c = n0 + wn + 16 * j + cl;
    bool cv = (c < Ncols);
    float bv = cv ? bias[c] : 0.f;
#pragma unroll
    for (int i = 0; i < 4; i++) {
      int rbase = m0 + wm + 16 * i + 4 * quad;
#pragma unroll
      for (int v = 0; v < 4; v++) {
        int rr = rbase + v;
        if (rr < M && cv) {
          float val = acc[i][j][v] + bv;
          size_t idx = (size_t)rr * Ncols + c;
          if constexpr (EPI == 0) {
            hio[idx] = val;
            obf[idx] = f2bf(val);
          } else if constexpr (EPI == 1) {
            obf[idx] = f2bf(val);
            sj[j] += val; s2j[j] += val * val;
          } else if constexpr (EPI == 2) {
            val += hio[idx];
            val = fmaxf(val, 0.f);
            hio[idx] = val;
            obf[idx] = f2bf(val);
          } else {
            val = fmaxf(val, 0.f);
            hio[idx] = val;
            obf[idx] = f2bf(val);
          }
        }
      }
    }
  }
  if constexpr (EPI == 1) {
    __syncthreads();
    statS[t < 256 ? t : 0] = 0.f;
    __syncthreads();
#pragma unroll
    for (int j = 0; j < 4; j++) {
      float s = sj[j], s2 = s2j[j];
      s += __shfl_xor(s, 16, 64);  s2 += __shfl_xor(s2, 16, 64);
      s += __shfl_xor(s, 32, 64);  s2 += __shfl_xor(s2, 32, 64);
      if (quad == 0) {
        int c = wn + 16 * j + cl;
        atomicAdd(&statS[c], s);
        atomicAdd(&statS[128 + c], s2);
      }
    }
    __syncthreads();
    if (t < 128) {
      atomicAdd(&stats[n0 + t], statS[t]);
      atomicAdd(&stats[Ncols + n0 + t], statS[128 + t]);
    }
  }
}

// ---------------- BN finalize: scale/shift ----------------
__global__ void bnfin_k(const float* __restrict__ stats, const float* __restrict__ g,
                        const float* __restrict__ be, float* __restrict__ ss, float inv_n) {
  int c = threadIdx.x;  // 256
  float mu = stats[c] * inv_n;
  float var = stats[256 + c] * inv_n - mu * mu;
  float rstd = rsqrtf(var + 1e-5f);
  float sc = rstd * g[c];
  ss[c] = sc;
  ss[256 + c] = be[c] - mu * sc;
}

// ---------------- pooling (batch is SORTED -> segment boundaries via bsearch) ---
__global__ void gseg_k(const int* __restrict__ bat, int* __restrict__ gb, int n) {
  int g = threadIdx.x;  // 128 threads, need 0..64
  if (g > GG) return;
  // lower_bound: first i with bat[i] >= g
  int lo = 0, hi = n;
  while (lo < hi) {
    int mid = (lo + hi) >> 1;
    if (bat[mid] < g) lo = mid + 1; else hi = mid;
  }
  gb[g] = lo;
}

// one block per graph; thread t: channel t&127, half t>>7; no atomics
__global__ __launch_bounds__(256) void gpool_k(
    const float* __restrict__ h, const int* __restrict__ gb,
    float* __restrict__ pooled, u16* __restrict__ pooledb, int coff) {
  __shared__ float s[256];
  int g = blockIdx.x;
  int t = threadIdx.x;
  int c = t & 127, half = t >> 7;
  int b0 = gb[g], b1 = gb[g + 1];
  float sum = 0.f;
  for (int n = b0 + half; n < b1; n += 2)
    sum += h[(size_t)n * 128 + c];
  s[t] = sum;
  __syncthreads();
  if (t < 128) {
    float v = s[t] + s[t + 128];
    float cnt = (float)(b1 - b0);
    v = v / fmaxf(cnt, 1.0f);
    pooled[g * 256 + coff + t] = v;
    pooledb[g * 256 + coff + t] = f2bf(v);
  }
}

// ---------------- final dot + sigmoid ----------------
__global__ void outk(const float* __restrict__ h2, const float* __restrict__ outW,
                     const float* __restrict__ outb, float* __restrict__ out) {
  int r = threadIdx.x;  // 64
  float s = outb[0];
  for (int k = 0; k < 64; k++) s += h2[r * 64 + k] * outW[k];
  out[r] = 1.0f / (1.0f + expf(-s));
}

extern "C" void kernel_launch(void* const* d_in, const int* in_sizes, int n_in,
                              void* d_out, int out_size, void* d_ws, size_t ws_size,
                              hipStream_t stream) {
  (void)in_sizes; (void)n_in; (void)out_size; (void)ws_size;
  const float* xin[2] = {(const float*)d_in[0], (const float*)d_in[3]};
  const int*   ei[2]  = {(const int*)d_in[1], (const int*)d_in[4]};
  const int*   bat[2] = {(const int*)d_in[2], (const int*)d_in[5]};
  const float *embW[2], *embB[2], *W1[2], *b1[2], *gam[2], *bet[2], *W2[2], *b2[2], *eps[2];
  for (int b = 0; b < 2; b++) {
    int o = 6 + b * 9;
    embW[b] = (const float*)d_in[o + 0]; embB[b] = (const float*)d_in[o + 1];
    W1[b]   = (const float*)d_in[o + 2]; b1[b]   = (const float*)d_in[o + 3];
    gam[b]  = (const float*)d_in[o + 4]; bet[b]  = (const float*)d_in[o + 5];
    W2[b]   = (const float*)d_in[o + 6]; b2[b]   = (const float*)d_in[o + 7];
    eps[b]  = (const float*)d_in[o + 8];
  }
  const float* fc1W = (const float*)d_in[24]; const float* fc1b = (const float*)d_in[25];
  const float* fc2W = (const float*)d_in[26]; const float* fc2b = (const float*)d_in[27];
  const float* outW = (const float*)d_in[28]; const float* outb = (const float*)d_in[29];

  char* base = (char*)d_ws; size_t off = 0;
  auto al = [&](size_t bytes) -> char* {
    char* p = base + off; off += (bytes + 255) & ~(size_t)255; return p;
  };
  float* h      = (float*)al((size_t)NN * DD * 4);
  u32*   hb     = (u32*)  al((size_t)NN * DD * 2);
  u32*   zb     = (u32*)  al((size_t)NN * DD * 2);
  u16*   tb     = (u16*)  al((size_t)NN * D2 * 2);
  int*   deg    = (int*)  al((size_t)NN * 4);
  int*   rowp   = (int*)  al((size_t)(NN + 1) * 4);
  int*   cur    = (int*)  al((size_t)NN * 4);
  int*   colx   = (int*)  al((size_t)EE * 4);
  int*   bsum   = (int*)  al(512 * 4);
  float* stats  = (float*)al(512 * 4);
  float* ssb    = (float*)al(512 * 4);
  float* pooled = (float*)al(GG * D2 * 4);
  u16*   pooledb= (u16*)  al(GG * D2 * 2);
  int*   gbnd   = (int*)  al((GG + 1) * 4);
  u16 *embWt[2], *W1t[2], *W2t[2];
  for (int b = 0; b < 2; b++) {
    embWt[b] = (u16*)al((size_t)DD * FIN * 2);
    W1t[b]   = (u16*)al((size_t)LL * D2 * DD * 2);
    W2t[b]   = (u16*)al((size_t)LL * DD * D2 * 2);
  }
  u16*   fc1Wt = (u16*)  al(256 * 256 * 2);
  u16*   fc2Wt = (u16*)  al(64 * 256 * 2);
  float* h1f   = (float*)al(64 * 256 * 4);
  u16*   h1b   = (u16*)  al(64 * 256 * 2);
  float* h2f   = (float*)al(64 * 64 * 4);
  u16*   h2b   = (u16*)  al(64 * 64 * 2);

  for (int b = 0; b < 2; b++) {
    wconv_k<<<(DD * FIN + 255) / 256, 256, 0, stream>>>(embW[b], embWt[b], FIN, DD, FIN * DD);
    wconv_k<<<(LL * DD * D2 + 255) / 256, 256, 0, stream>>>(W1[b], W1t[b], DD, D2, LL * DD * D2);
    wconv_k<<<(LL * DD * D2 + 255) / 256, 256, 0, stream>>>(W2[b], W2t[b], D2, DD, LL * DD * D2);
  }
  wconv_k<<<(256 * 256 + 255) / 256, 256, 0, stream>>>(fc1W, fc1Wt, 256, 256, 256 * 256);
  wconv_k<<<(256 * 64 + 255) / 256, 256, 0, stream>>>(fc2W, fc2Wt, 256, 64, 256 * 64);

  const int gx = (NN + 127) / 128;
  const int nbk = (NN + 255) / 256;  // 391
  for (int b = 0; b < 2; b++) {
    const int* esrc = ei[b];
    const int* edst = ei[b] + EE;
    hipMemsetAsync(deg, 0, (size_t)NN * 4, stream);
    hist_k<<<(EE + 255) / 256, 256, 0, stream>>>(edst, deg, EE);
    scan1_k<<<nbk, 256, 0, stream>>>(deg, bsum, NN);
    scan2_k<<<1, 512, 0, stream>>>(bsum, nbk);
    scan3_k<<<nbk, 256, 0, stream>>>(deg, bsum, rowp, NN, nbk);
    hipMemcpyAsync(cur, rowp, (size_t)NN * 4, hipMemcpyDeviceToDevice, stream);
    fill_k<<<(EE + 255) / 256, 256, 0, stream>>>(esrc, edst, cur, colx, EE);

    gemm_k<0, 0><<<dim3(gx, 1), 256, 0, stream>>>(xin[b], embWt[b], embB[b], nullptr,
                                                  h, (u16*)hb, nullptr, NN, FIN, DD);
    for (int l = 0; l < LL; l++) {
      zin_k<<<(NN + 3) / 4, 256, 0, stream>>>(h, hb, rowp, colx, eps[b] + l, zb, NN);
      hipMemsetAsync(stats, 0, 512 * 4, stream);
      gemm_k<1, 1><<<dim3(gx, 2), 256, 0, stream>>>(zb, W1t[b] + l * D2 * DD, b1[b] + l * D2,
                                                    nullptr, nullptr, tb, stats, NN, DD, D2);
      bnfin_k<<<1, 256, 0, stream>>>(stats, gam[b] + l * D2, bet[b] + l * D2, ssb, 1.0f / NN);
      gemm_k<2, 2><<<dim3(gx, 1), 256, 0, stream>>>(tb, W2t[b] + l * DD * D2, b2[b] + l * DD,
                                                    ssb, h, (u16*)hb, nullptr, NN, D2, DD);
    }
    gseg_k<<<1, 128, 0, stream>>>(bat[b], gbnd, NN);
    gpool_k<<<GG, 256, 0, stream>>>(h, gbnd, pooled, pooledb, b * DD);
  }
  gemm_k<1, 3><<<dim3(1, 2), 256, 0, stream>>>(pooledb, fc1Wt, fc1b, nullptr,
                                               h1f, h1b, nullptr, GG, 256, 256);
  gemm_k<1, 3><<<dim3(1, 1), 256, 0, stream>>>(h1b, fc2Wt, fc2b, nullptr,
                                               h2f, h2b, nullptr, GG, 256, 64);
  outk<<<1, 64, 0, stream>>>(h2f, outW, outb, (float*)d_out);
}